// Round 4
// baseline (57.764 us; speedup 1.0000x reference)
//
#include <hip/hip_runtime.h>

// 2x2 non-overlapping max pool, fp32.
// X: (B=16, C=64, H=256, W=256) -> out: (16, 64, 128, 128)
// Memory-bound streaming. This version makes EVERY load instruction
// lane-contiguous: thread u in a half-wave loads float4 at u*16B within
// a 512B half-row segment (row first-half / second-half x 2 input rows),
// instead of 2 adjacent float4s per thread (which gave a 32B-strided
// 16B-per-lane pattern = 2x the lines touched per instruction).
// Outputs: two float2 stores (cols 2u and 64+2u), lane-contiguous.

#define W_IN 256
#define H_IN 256
#define W_OUT 128
#define H_OUT 128

typedef float f4 __attribute__((ext_vector_type(4)));
typedef float f2 __attribute__((ext_vector_type(2)));

__global__ __launch_bounds__(256) void maxpool2x2_kernel(
    const float* __restrict__ X, float* __restrict__ out) {
    int t = blockIdx.x * 256 + threadIdx.x;
    int u = t & 31;           // position within output row (half-row unit)
    int r = t >> 5;           // output row (b,c,h_out flattened)
    int p     = r >> 7;       // plane = b*C + c
    int h_out = r & 127;

    long base = (long)p * (H_IN * W_IN) + (long)(2 * h_out) * W_IN;
    const float* row0 = X + base + u * 4;
    const float* row1 = row0 + W_IN;

    // Each instruction: 32 lanes x 16B contiguous = 512B segment.
    f4 A0 = __builtin_nontemporal_load(reinterpret_cast<const f4*>(row0));
    f4 A1 = __builtin_nontemporal_load(reinterpret_cast<const f4*>(row0 + 128));
    f4 B0 = __builtin_nontemporal_load(reinterpret_cast<const f4*>(row1));
    f4 B1 = __builtin_nontemporal_load(reinterpret_cast<const f4*>(row1 + 128));

    f2 o0, o1;
    o0.x = fmaxf(fmaxf(A0.x, A0.y), fmaxf(B0.x, B0.y));
    o0.y = fmaxf(fmaxf(A0.z, A0.w), fmaxf(B0.z, B0.w));
    o1.x = fmaxf(fmaxf(A1.x, A1.y), fmaxf(B1.x, B1.y));
    o1.y = fmaxf(fmaxf(A1.z, A1.w), fmaxf(B1.z, B1.w));

    long ob = (long)r * W_OUT + 2 * u;
    __builtin_nontemporal_store(o0, reinterpret_cast<f2*>(out + ob));
    __builtin_nontemporal_store(o1, reinterpret_cast<f2*>(out + ob + 64));
}

extern "C" void kernel_launch(void* const* d_in, const int* in_sizes, int n_in,
                              void* d_out, int out_size, void* d_ws, size_t ws_size,
                              hipStream_t stream) {
    const float* X = (const float*)d_in[0];
    float* out = (float*)d_out;

    int n_threads = out_size / 4;      // 4,194,304 (4 outputs per thread)
    int grid = n_threads / 256;        // 16,384 blocks, exact cover
    maxpool2x2_kernel<<<grid, 256, 0, stream>>>(X, out);
}